// Round 1
// baseline (2067.532 us; speedup 1.0000x reference)
//
#include <hip/hip_runtime.h>
#include <math.h>

static constexpr int B_ = 8, C_ = 512, T_ = 2048;
static constexpr int C3_ = 3 * C_;
static constexpr float INV_TEMP = 1.0f / 0.07f;

// ---------------------------------------------------------------------------
// Generic 64x64-tile fp32 GEMM:  C[m,n] = sum_k A'[m,k] * B'[k,n]
//   TA ? A'[m,k] = A[k*lda + m] : A[m*lda + k]
//   TB ? B'[k,n] = B[n*ldb + k] : B[k*ldb + n]
// EPI: multiply output by rs[m]*cs[n]*scale (used for the score GEMM where the
// channel-L2 normalization and 1/TEMP are folded in).
// Batched over blockIdx.z with element strides sA/sB/sC.
// LDS layout As[k][m], Bs[k][n]; write patterns keep bank aliasing <= 2-way.
// ---------------------------------------------------------------------------
template<bool TA, bool TB, bool EPI>
__global__ __launch_bounds__(256)
void gemm64(const float* __restrict__ A, const float* __restrict__ B,
            float* __restrict__ C, int K, int lda, int ldb, int ldc,
            long long sA, long long sB, long long sC,
            const float* __restrict__ rs, const float* __restrict__ cs,
            float scale)
{
  const int bz = blockIdx.z;
  A += (long long)bz * sA;
  B += (long long)bz * sB;
  C += (long long)bz * sC;
  const int row0 = blockIdx.y * 64, col0 = blockIdx.x * 64;
  const int tid = threadIdx.x;
  const int tx = tid & 15, ty = tid >> 4;
  __shared__ float As[16][64], Bs[16][64];
  float acc[4][4] = {};

  for (int kk = 0; kk < K; kk += 16) {
    if (!TA) {
      // A row-major [M,K]: load float4 along k, scatter to As[k][m]
      const int k0 = (tid & 3) << 2, m = tid >> 2;
      const float4 v = *(const float4*)(A + (long long)(row0 + m) * lda + (kk + k0));
      As[k0+0][m] = v.x; As[k0+1][m] = v.y; As[k0+2][m] = v.z; As[k0+3][m] = v.w;
    } else {
      // A stored [K,M]: coalesced along m
      const int m = tid & 63, k0 = tid >> 6;
      #pragma unroll
      for (int r = 0; r < 4; ++r)
        As[k0 + r*4][m] = A[(long long)(kk + k0 + r*4) * lda + (row0 + m)];
    }
    if (!TB) {
      // B stored [K,N]: coalesced along n
      const int n = tid & 63, k0 = tid >> 6;
      #pragma unroll
      for (int r = 0; r < 4; ++r)
        Bs[k0 + r*4][n] = B[(long long)(kk + k0 + r*4) * ldb + (col0 + n)];
    } else {
      // B stored [N,K]: load float4 along k, scatter to Bs[k][n]
      const int k0 = (tid & 3) << 2, n = tid >> 2;
      const float4 v = *(const float4*)(B + (long long)(col0 + n) * ldb + (kk + k0));
      Bs[k0+0][n] = v.x; Bs[k0+1][n] = v.y; Bs[k0+2][n] = v.z; Bs[k0+3][n] = v.w;
    }
    __syncthreads();
    #pragma unroll
    for (int k = 0; k < 16; ++k) {
      const float4 a4 = *(const float4*)&As[k][ty << 2];
      const float4 b4 = *(const float4*)&Bs[k][tx << 2];
      const float a[4] = {a4.x, a4.y, a4.z, a4.w};
      const float b[4] = {b4.x, b4.y, b4.z, b4.w};
      #pragma unroll
      for (int i = 0; i < 4; ++i)
        #pragma unroll
        for (int j = 0; j < 4; ++j)
          acc[i][j] = fmaf(a[i], b[j], acc[i][j]);
    }
    __syncthreads();
  }

  #pragma unroll
  for (int i = 0; i < 4; ++i) {
    const int m = row0 + (ty << 2) + i;
    float* dst = C + (long long)m * ldc + col0 + (tx << 2);
    float4 o;
    if (EPI) {
      const float rowf = rs[m] * scale;
      const int n = col0 + (tx << 2);
      o.x = acc[i][0] * rowf * cs[n+0];
      o.y = acc[i][1] * rowf * cs[n+1];
      o.z = acc[i][2] * rowf * cs[n+2];
      o.w = acc[i][3] * rowf * cs[n+3];
    } else {
      o.x = acc[i][0]; o.y = acc[i][1]; o.z = acc[i][2]; o.w = acc[i][3];
    }
    *(float4*)dst = o;
  }
}

// ---------------------------------------------------------------------------
// Depthwise conv, kernel 3, zero pad 1, over T (cross-correlation, XLA conv
// semantics: y[t] = w0*x[t-1] + w1*x[t] + w2*x[t+1]). One thread per element.
// ---------------------------------------------------------------------------
__global__ __launch_bounds__(256)
void dw3(const float* __restrict__ src, const float* __restrict__ wdw,
         float* __restrict__ dst)
{
  const long long idx = (long long)blockIdx.x * 256 + threadIdx.x;  // [B*3C*T)
  const int t = (int)(idx % T_);
  const long long rowi = idx / T_;          // b*3C + o
  const int o = (int)(rowi % C3_);
  const float* row = src + rowi * T_;
  const float xm = (t > 0)      ? row[t-1] : 0.f;
  const float x0 = row[t];
  const float xp = (t < T_ - 1) ? row[t+1] : 0.f;
  dst[idx] = fmaf(wdw[o*3+0], xm, fmaf(wdw[o*3+1], x0, wdw[o*3+2] * xp));
}

// ---------------------------------------------------------------------------
// Channel L2 norm stats for q (z=0) and k (z=1): inv_n[b,t] = 1/max(||.||,eps)
// ---------------------------------------------------------------------------
__global__ __launch_bounds__(256)
void norms(const float* __restrict__ qkv_dw, float* __restrict__ inv_nq,
           float* __restrict__ inv_nk)
{
  const int t = blockIdx.x * 256 + threadIdx.x;
  const int b = blockIdx.y;
  const int part = blockIdx.z;  // 0=q, 1=k
  const float* base = qkv_dw + ((long long)b * C3_ + part * C_) * T_ + t;
  float ss = 0.f;
  for (int c = 0; c < C_; ++c) {
    const float v = base[(long long)c * T_];
    ss = fmaf(v, v, ss);
  }
  const float inv = 1.0f / fmaxf(sqrtf(ss), 1e-12f);
  (part == 0 ? inv_nq : inv_nk)[b * T_ + t] = inv;
}

// ---------------------------------------------------------------------------
// Row softmax over T_ elements, one block (256 threads) per row, in place.
// ---------------------------------------------------------------------------
__global__ __launch_bounds__(256)
void softmax_row(float* __restrict__ attn)
{
  float* p = attn + (long long)blockIdx.x * T_;
  const int tid = threadIdx.x;
  __shared__ float red[256];
  float vals[T_ / 256];
  float mx = -1e30f;
  #pragma unroll
  for (int i = 0; i < T_ / 256; ++i) {
    vals[i] = p[tid + i * 256];
    mx = fmaxf(mx, vals[i]);
  }
  red[tid] = mx; __syncthreads();
  for (int s = 128; s > 0; s >>= 1) {
    if (tid < s) red[tid] = fmaxf(red[tid], red[tid + s]);
    __syncthreads();
  }
  mx = red[0]; __syncthreads();
  float sum = 0.f;
  #pragma unroll
  for (int i = 0; i < T_ / 256; ++i) {
    vals[i] = __expf(vals[i] - mx);
    sum += vals[i];
  }
  red[tid] = sum; __syncthreads();
  for (int s = 128; s > 0; s >>= 1) {
    if (tid < s) red[tid] += red[tid + s];
    __syncthreads();
  }
  const float inv = 1.0f / red[0];
  #pragma unroll
  for (int i = 0; i < T_ / 256; ++i) p[tid + i * 256] = vals[i] * inv;
}

// ---------------------------------------------------------------------------
// Workspace layout (floats):
//   [0, 25165824)             qkv_dw  [B,3C,T]
//   [25165824, 50331648)      regionB: qkv_raw [B,3C,T]  (dead after dw3)
//                             then reused as attn [T,T] + out_av [B,C,T]
//   [50331648, +B*T)          inv_nq
//   [+B*T, +2*B*T)            inv_nk
// Total ~201.6 MB.
// ---------------------------------------------------------------------------
extern "C" void kernel_launch(void* const* d_in, const int* in_sizes, int n_in,
                              void* d_out, int out_size, void* d_ws, size_t ws_size,
                              hipStream_t stream)
{
  const float* x      = (const float*)d_in[0];  // [B,C,T]
  const float* w_qkv  = (const float*)d_in[1];  // [3C,C,1]
  const float* w_dw   = (const float*)d_in[2];  // [3C,1,3]
  const float* w_proj = (const float*)d_in[3];  // [C,C,1]
  float* out = (float*)d_out;                   // [B,C,T]

  float* ws = (float*)d_ws;
  const long long nQKV = (long long)B_ * C3_ * T_;     // 25165824
  float* qkv_dw  = ws;
  float* regionB = ws + nQKV;
  float* qkv_raw = regionB;
  float* attn    = regionB;                            // T*T, reuses qkv_raw
  float* out_av  = regionB + (long long)T_ * T_;       // B*C*T
  float* inv_nq  = ws + 2 * nQKV;
  float* inv_nk  = inv_nq + B_ * T_;

  // 1) qkv_raw[b] = W_qkv[3C,C] @ x[b][C,T]
  gemm64<false, false, false><<<dim3(T_/64, C3_/64, B_), 256, 0, stream>>>(
      w_qkv, x, qkv_raw, C_, C_, T_, T_,
      0LL, (long long)C_ * T_, (long long)C3_ * T_, nullptr, nullptr, 1.f);

  // 2) depthwise conv 3 (elementwise-parallel)
  dw3<<<(int)(nQKV / 256), 256, 0, stream>>>(qkv_raw, w_dw, qkv_dw);

  // 3) channel-L2 stats for q,k
  norms<<<dim3(T_/256, B_, 2), 256, 0, stream>>>(qkv_dw, inv_nq, inv_nk);

  // 4) per batch: scores -> softmax -> AV
  for (int b = 0; b < B_; ++b) {
    const float* q = qkv_dw + (long long)b * C3_ * T_;
    const float* k = q + (long long)C_ * T_;
    const float* v = q + 2LL * C_ * T_;

    // S[t,s] = (sum_c q[c,t] k[c,s]) * inv_nq[t] * inv_nk[s] / TEMP
    gemm64<true, false, true><<<dim3(T_/64, T_/64, 1), 256, 0, stream>>>(
        q, k, attn, C_, T_, T_, T_,
        0LL, 0LL, 0LL, inv_nq + b * T_, inv_nk + b * T_, INV_TEMP);

    softmax_row<<<T_, 256, 0, stream>>>(attn);

    // out_av[c,t] = sum_s v[c,s] * attn[t,s]
    gemm64<false, true, false><<<dim3(T_/64, C_/64, 1), 256, 0, stream>>>(
        v, attn, out_av + (long long)b * C_ * T_, T_, T_, T_, T_,
        0LL, 0LL, 0LL, nullptr, nullptr, 1.f);
  }

  // 5) out[b] = W_proj[C,C] @ out_av[b][C,T]
  gemm64<false, false, false><<<dim3(T_/64, C_/64, B_), 256, 0, stream>>>(
      w_proj, out_av, out, C_, C_, T_, T_,
      0LL, (long long)C_ * T_, (long long)C_ * T_, nullptr, nullptr, 1.f);
}

// Round 2
// 380.863 us; speedup vs baseline: 5.4286x; 5.4286x over previous
//
#include <hip/hip_runtime.h>
#include <math.h>

static constexpr int B_ = 8, C_ = 512, T_ = 2048, C3_ = 1536;
static constexpr float INV_TEMP = 1.0f / 0.07f;

typedef __attribute__((ext_vector_type(8))) short short8;
typedef __attribute__((ext_vector_type(4))) float floatx4;

__device__ __forceinline__ float b2f(unsigned short u) {
  union { unsigned int i; float f; } v; v.i = ((unsigned int)u) << 16; return v.f;
}
__device__ __forceinline__ unsigned short f2b(float f) {
  union { float f; unsigned int i; } v; v.f = f;
  const unsigned int x = v.i;
  return (unsigned short)((x + 0x7FFFu + ((x >> 16) & 1u)) >> 16);
}
__device__ __forceinline__ void gld16(const unsigned short* g, unsigned short* l) {
  __builtin_amdgcn_global_load_lds(
      (const __attribute__((address_space(1))) void*)g,
      (__attribute__((address_space(3))) void*)l, 16, 0, 0);
}

// ---------------------------------------------------------------------------
// TN-form bf16 MFMA GEMM: C[m,n] = sum_k A[m,k]*B[n,k], A:[M,K] B:[N,K],
// both k-contiguous bf16. 128x128 tile, BK=32, 256 thr = 4 waves (2x2 of
// 64x64), 16x16x32 MFMA. Staging via global_load_lds width 16 with XOR
// granule swizzle g_stored(m,q)=q^((m>>1)&3) -> 2-way (free) LDS banks.
// OUT_BF16: write bf16, else fp32. EPI: *= rs[m]*cs[n]*scale (per-z offset
// rcStride). Batched over blockIdx.z.
// ---------------------------------------------------------------------------
template<bool OUT_BF16, bool EPI>
__global__ __launch_bounds__(256)
void gemm_tn(const unsigned short* __restrict__ A, const unsigned short* __restrict__ B,
             void* __restrict__ Cout, int K, int lda, int ldb, int ldc,
             long long sA, long long sB, long long sC,
             const float* __restrict__ rs, const float* __restrict__ cs,
             int rcStride, float scale)
{
  const int bz = blockIdx.z;
  A += (long long)bz * sA;
  B += (long long)bz * sB;
  if (EPI) { rs += (long long)bz * rcStride; cs += (long long)bz * rcStride; }
  const int m0 = blockIdx.y * 128, n0 = blockIdx.x * 128;
  const int tid = threadIdx.x;
  const int w = tid >> 6, lane = tid & 63;
  const int wm = (w >> 1) * 64, wn = (w & 1) * 64;
  const int rl = lane & 15, qd = lane >> 4;

  __shared__ __align__(16) unsigned short As[128 * 32];
  __shared__ __align__(16) unsigned short Bs[128 * 32];

  // staging: wave w covers rows 32w..32w+31 of each tile (2 chunks of 16 rows)
  const int sr = lane >> 2, sg = lane & 3;
  const int ml0 = 32 * w + sr, ml1 = 32 * w + 16 + sr;
  const int q0 = sg ^ ((ml0 >> 1) & 3), q1 = sg ^ ((ml1 >> 1) & 3);
  const unsigned short* gA0 = A + (long long)(m0 + ml0) * lda + q0 * 8;
  const unsigned short* gA1 = A + (long long)(m0 + ml1) * lda + q1 * 8;
  const unsigned short* gB0 = B + (long long)(n0 + ml0) * ldb + q0 * 8;
  const unsigned short* gB1 = B + (long long)(n0 + ml1) * ldb + q1 * 8;
  unsigned short* lA0 = As + (32 * w) * 32;        // wave-uniform chunk bases
  unsigned short* lA1 = As + (32 * w + 16) * 32;
  unsigned short* lB0 = Bs + (32 * w) * 32;
  unsigned short* lB1 = Bs + (32 * w + 16) * 32;

  // fragment read offsets (swizzle-corrected)
  int aoff[4], boff[4];
  #pragma unroll
  for (int i = 0; i < 4; ++i) {
    const int mr = wm + i * 16 + rl;
    aoff[i] = mr * 32 + ((qd ^ ((mr >> 1) & 3)) * 8);
    const int nr = wn + i * 16 + rl;
    boff[i] = nr * 32 + ((qd ^ ((nr >> 1) & 3)) * 8);
  }

  floatx4 acc[4][4];
  #pragma unroll
  for (int i = 0; i < 4; ++i)
    #pragma unroll
    for (int j = 0; j < 4; ++j) acc[i][j] = 0.0f;

  for (int kk = 0; kk < K; kk += 32) {
    gld16(gA0 + kk, lA0);
    gld16(gA1 + kk, lA1);
    gld16(gB0 + kk, lB0);
    gld16(gB1 + kk, lB1);
    __syncthreads();                       // drains vmcnt -> tiles ready
    short8 fa[4], fb[4];
    #pragma unroll
    for (int i = 0; i < 4; ++i) fa[i] = *(const short8*)(As + aoff[i]);
    #pragma unroll
    for (int j = 0; j < 4; ++j) fb[j] = *(const short8*)(Bs + boff[j]);
    #pragma unroll
    for (int i = 0; i < 4; ++i)
      #pragma unroll
      for (int j = 0; j < 4; ++j)
        acc[i][j] = __builtin_amdgcn_mfma_f32_16x16x32_bf16(fa[i], fb[j], acc[i][j], 0, 0, 0);
    __syncthreads();                       // LDS reads done before next stage
  }

  // epilogue: C/D layout col=lane&15, row=(lane>>4)*4+reg
  #pragma unroll
  for (int i = 0; i < 4; ++i) {
    #pragma unroll
    for (int r = 0; r < 4; ++r) {
      const int row = m0 + wm + i * 16 + qd * 4 + r;
      const float rowf = EPI ? rs[row] * scale : 0.f;
      #pragma unroll
      for (int j = 0; j < 4; ++j) {
        const int col = n0 + wn + j * 16 + rl;
        float v = acc[i][j][r];
        if (EPI) v *= rowf * cs[col];
        const long long idx = (long long)bz * sC + (long long)row * ldc + col;
        if (OUT_BF16) ((unsigned short*)Cout)[idx] = f2b(v);
        else          ((float*)Cout)[idx] = v;
      }
    }
  }
}

// ---------------------------------------------------------------------------
// x [B,C,T] fp32 -> xT [B,T,C] bf16 (transpose-convert, 32x32 LDS tiles)
// ---------------------------------------------------------------------------
__global__ __launch_bounds__(256)
void conv_xT(const float* __restrict__ x, unsigned short* __restrict__ xT)
{
  const int b = blockIdx.z, t0 = blockIdx.x * 32, c0 = blockIdx.y * 32;
  const int tx = threadIdx.x & 31, ty = threadIdx.x >> 5;
  __shared__ float tile[32][33];
  const float* src = x + (long long)b * C_ * T_;
  #pragma unroll
  for (int r = 0; r < 4; ++r)
    tile[ty + 8 * r][tx] = src[(long long)(c0 + ty + 8 * r) * T_ + t0 + tx];
  __syncthreads();
  unsigned short* dst = xT + (long long)b * T_ * C_;
  #pragma unroll
  for (int r = 0; r < 4; ++r)
    dst[(long long)(t0 + ty + 8 * r) * C_ + c0 + tx] = f2b(tile[tx][ty + 8 * r]);
}

__global__ __launch_bounds__(256)
void conv_bf(const float* __restrict__ in, unsigned short* __restrict__ out, int n)
{
  const int i = blockIdx.x * 256 + threadIdx.x;
  if (i < n) out[i] = f2b(in[i]);
}

// ---------------------------------------------------------------------------
// Depthwise-3 (zero pad) on v channels [2C,3C): bf16 in [B,3C,T] -> v [B,C,T]
// ---------------------------------------------------------------------------
__global__ __launch_bounds__(256)
void dw_v(const unsigned short* __restrict__ qkv, const float* __restrict__ wdw,
          unsigned short* __restrict__ vout)
{
  const long long idx = (long long)blockIdx.x * 256 + threadIdx.x;  // [B*C*T)
  const int t = (int)(idx % T_);
  const long long rem = idx / T_;
  const int c = (int)(rem % C_), b = (int)(rem / C_);
  const unsigned short* src = qkv + ((long long)(b * C3_ + 2 * C_ + c)) * T_;
  const float* wp = wdw + (2 * C_ + c) * 3;
  const float xm = (t > 0)      ? b2f(src[t - 1]) : 0.f;
  const float x0 = b2f(src[t]);
  const float xp = (t < T_ - 1) ? b2f(src[t + 1]) : 0.f;
  vout[(long long)(b * C_ + c) * T_ + t] = f2b(fmaf(wp[0], xm, fmaf(wp[1], x0, wp[2] * xp)));
}

// ---------------------------------------------------------------------------
// Depthwise-3 + transpose for q (p=0) / k (p=1): [B,3C,T] -> [B,T,C] bf16
// ---------------------------------------------------------------------------
__global__ __launch_bounds__(256)
void dw_qk_t(const unsigned short* __restrict__ qkv, const float* __restrict__ wdw,
             unsigned short* __restrict__ qT, unsigned short* __restrict__ kT)
{
  const int bz = blockIdx.z, b = bz >> 1, p = bz & 1;
  const int t0 = blockIdx.x * 32, c0 = blockIdx.y * 32;
  const int tx = threadIdx.x & 31, ty = threadIdx.x >> 5;
  __shared__ float tin[32][34];   // [c][t-1 .. t+32]
  __shared__ float tout[32][33];  // [t][c]
  const int chb = b * C3_ + p * C_;
  #pragma unroll
  for (int r = 0; r < 4; ++r) {
    const int cy = ty + 8 * r;
    const unsigned short* src = qkv + (long long)(chb + c0 + cy) * T_;
    int t = t0 - 1 + tx;
    tin[cy][tx] = (t >= 0 && t < T_) ? b2f(src[t]) : 0.f;
    if (tx < 2) {
      const int t2 = t0 + 31 + tx;
      tin[cy][32 + tx] = (t2 < T_) ? b2f(src[t2]) : 0.f;
    }
  }
  __syncthreads();
  #pragma unroll
  for (int r = 0; r < 4; ++r) {
    const int cy = ty + 8 * r;
    const float* wp = wdw + (long long)(p * C_ + c0 + cy) * 3;
    tout[tx][cy] = fmaf(wp[0], tin[cy][tx], fmaf(wp[1], tin[cy][tx + 1], wp[2] * tin[cy][tx + 2]));
  }
  __syncthreads();
  unsigned short* dst = (p == 0 ? qT : kT) + (long long)b * T_ * C_;
  #pragma unroll
  for (int r = 0; r < 4; ++r)
    dst[(long long)(t0 + ty + 8 * r) * C_ + c0 + tx] = f2b(tout[ty + 8 * r][tx]);
}

// ---------------------------------------------------------------------------
// Row L2-norm stats from bf16 [B*T, C] rows: inv = 1/max(||row||,eps)
// One wave per row (512 = 64 lanes x 8).
// ---------------------------------------------------------------------------
__global__ __launch_bounds__(256)
void norms_k(const unsigned short* __restrict__ qT, const unsigned short* __restrict__ kT,
             float* __restrict__ inv_nq, float* __restrict__ inv_nk)
{
  const int wave = threadIdx.x >> 6, lane = threadIdx.x & 63;
  const long long row = (long long)blockIdx.x * 4 + wave;
  const unsigned short* src = (blockIdx.y == 0 ? qT : kT) + row * C_ + lane * 8;
  const uint4 u = *(const uint4*)src;
  float ss = 0.f;
  const unsigned int uu[4] = {u.x, u.y, u.z, u.w};
  #pragma unroll
  for (int i = 0; i < 4; ++i) {
    const float lo = b2f(uu[i] & 0xFFFF), hi = b2f(uu[i] >> 16);
    ss = fmaf(lo, lo, ss); ss = fmaf(hi, hi, ss);
  }
  #pragma unroll
  for (int m = 32; m; m >>= 1) ss += __shfl_xor(ss, m);
  if (lane == 0)
    (blockIdx.y == 0 ? inv_nq : inv_nk)[row] = 1.f / fmaxf(sqrtf(ss), 1e-12f);
}

// ---------------------------------------------------------------------------
// Row softmax: fp32 [rows, T] -> bf16 [rows, T]. 256 thr, 8 elems/thread.
// ---------------------------------------------------------------------------
__global__ __launch_bounds__(256)
void softmax_bf(const float* __restrict__ S, unsigned short* __restrict__ P)
{
  const float* src = S + (long long)blockIdx.x * T_;
  unsigned short* dst = P + (long long)blockIdx.x * T_;
  const int tid = threadIdx.x;
  __shared__ float red[256];
  const float4 v0 = ((const float4*)src)[tid * 2];
  const float4 v1 = ((const float4*)src)[tid * 2 + 1];
  float vals[8] = {v0.x, v0.y, v0.z, v0.w, v1.x, v1.y, v1.z, v1.w};
  float mx = vals[0];
  #pragma unroll
  for (int i = 1; i < 8; ++i) mx = fmaxf(mx, vals[i]);
  red[tid] = mx; __syncthreads();
  for (int s = 128; s > 0; s >>= 1) {
    if (tid < s) red[tid] = fmaxf(red[tid], red[tid + s]);
    __syncthreads();
  }
  mx = red[0]; __syncthreads();
  float sum = 0.f;
  #pragma unroll
  for (int i = 0; i < 8; ++i) { vals[i] = __expf(vals[i] - mx); sum += vals[i]; }
  red[tid] = sum; __syncthreads();
  for (int s = 128; s > 0; s >>= 1) {
    if (tid < s) red[tid] += red[tid + s];
    __syncthreads();
  }
  const float inv = 1.f / red[0];
  unsigned short o[8];
  #pragma unroll
  for (int i = 0; i < 8; ++i) o[i] = f2b(vals[i] * inv);
  uint4 pk;
  pk.x = (unsigned int)o[0] | ((unsigned int)o[1] << 16);
  pk.y = (unsigned int)o[2] | ((unsigned int)o[3] << 16);
  pk.z = (unsigned int)o[4] | ((unsigned int)o[5] << 16);
  pk.w = (unsigned int)o[6] | ((unsigned int)o[7] << 16);
  ((uint4*)dst)[tid] = pk;
}

// ---------------------------------------------------------------------------
// Workspace arena (bytes), total ~185.1 MB:
//  [0,   64M)  scores fp32 (4*T*T*4) — early: xT_bf(16M) + wqkv_bf; late: av_t
//  [64M, 80M)  qT   [80M, 96M) kT   [96M,112M) v
//  [112M,176M) attn bf16 (8*T*T*2) — early: qkv_bf (48M, dead after dw)
//  [176M, ..)  wproj_bf, inv_nq, inv_nk
// ---------------------------------------------------------------------------
extern "C" void kernel_launch(void* const* d_in, const int* in_sizes, int n_in,
                              void* d_out, int out_size, void* d_ws, size_t ws_size,
                              hipStream_t stream)
{
  const float* x      = (const float*)d_in[0];
  const float* w_qkv  = (const float*)d_in[1];
  const float* w_dw   = (const float*)d_in[2];
  const float* w_proj = (const float*)d_in[3];
  float* out = (float*)d_out;

  char* base = (char*)d_ws;
  float*          scores  = (float*)base;
  unsigned short* xT      = (unsigned short*)base;                    // alias
  unsigned short* wqkv_bf = (unsigned short*)(base + 16777216);       // alias
  unsigned short* av_t    = (unsigned short*)base;                    // alias (late)
  char* p = base + 67108864;
  unsigned short* qT = (unsigned short*)p; p += 16777216;
  unsigned short* kT = (unsigned short*)p; p += 16777216;
  unsigned short* vb = (unsigned short*)p; p += 16777216;
  unsigned short* attn    = (unsigned short*)p;
  unsigned short* qkv_bf  = (unsigned short*)p;                       // alias (early)
  p += 67108864;
  unsigned short* wproj_bf = (unsigned short*)p; p += 524288;
  float* inv_nq = (float*)p; p += 65536;
  float* inv_nk = (float*)p;

  const long long TC = (long long)T_ * C_, TT = (long long)T_ * T_;

  // 0) conversions
  conv_xT<<<dim3(T_ / 32, C_ / 32, B_), 256, 0, stream>>>(x, xT);
  conv_bf<<<(C3_ * C_) / 256, 256, 0, stream>>>(w_qkv, wqkv_bf, C3_ * C_);
  conv_bf<<<(C_ * C_) / 256, 256, 0, stream>>>(w_proj, wproj_bf, C_ * C_);

  // 1) qkv[b][o][t] = sum_c wqkv[o][c] * x[c][t]
  gemm_tn<true, false><<<dim3(16, 12, B_), 256, 0, stream>>>(
      wqkv_bf, xT, qkv_bf, C_, C_, C_, T_,
      0LL, TC, (long long)C3_ * T_, nullptr, nullptr, 0, 1.f);

  // 2) depthwise conv
  dw_v<<<(int)(((long long)B_ * C_ * T_) / 256), 256, 0, stream>>>(qkv_bf, w_dw, vb);
  dw_qk_t<<<dim3(T_ / 32, C_ / 32, B_ * 2), 256, 0, stream>>>(qkv_bf, w_dw, qT, kT);

  // 3) channel-L2 stats (from bf16 values — exact normalization of rounded vecs)
  norms_k<<<dim3((B_ * T_) / 4, 2), 256, 0, stream>>>(qT, kT, inv_nq, inv_nk);

  // 4) scores + softmax, two half-batches of 4 (scores buffer reused)
  for (int h = 0; h < 2; ++h) {
    const long long o = (long long)h * 4;
    gemm_tn<false, true><<<dim3(16, 16, 4), 256, 0, stream>>>(
        qT + o * TC, kT + o * TC, scores, C_, C_, C_, T_,
        TC, TC, TT, inv_nq + o * T_, inv_nk + o * T_, T_, INV_TEMP);
    softmax_bf<<<4 * T_, 256, 0, stream>>>(scores, attn + o * TT);
  }

  // 5) av_t[b][t][c] = sum_s attn[t][s] * v[c][s]
  gemm_tn<true, false><<<dim3(4, 16, B_), 256, 0, stream>>>(
      attn, vb, av_t, T_, T_, T_, C_,
      TT, (long long)C_ * T_, TC, nullptr, nullptr, 0, 1.f);

  // 6) out[b][o][t] = sum_c wproj[o][c] * av_t[t][c]
  gemm_tn<false, false><<<dim3(16, 4, B_), 256, 0, stream>>>(
      wproj_bf, av_t, out, C_, C_, C_, T_,
      0LL, TC, (long long)C_ * T_, nullptr, nullptr, 0, 1.f);
}

// Round 3
// 367.440 us; speedup vs baseline: 5.6269x; 1.0365x over previous
//
#include <hip/hip_runtime.h>
#include <math.h>

static constexpr int B_ = 8, C_ = 512, T_ = 2048, C3_ = 1536;
static constexpr float INV_TEMP = 1.0f / 0.07f;

typedef __attribute__((ext_vector_type(8))) short short8;
typedef __attribute__((ext_vector_type(4))) float floatx4;

__device__ __forceinline__ float b2f(unsigned short u) {
  union { unsigned int i; float f; } v; v.i = ((unsigned int)u) << 16; return v.f;
}
__device__ __forceinline__ unsigned short f2b(float f) {
  union { float f; unsigned int i; } v; v.f = f;
  const unsigned int x = v.i;
  return (unsigned short)((x + 0x7FFFu + ((x >> 16) & 1u)) >> 16);
}
__device__ __forceinline__ void gld16(const unsigned short* g, unsigned short* l) {
  __builtin_amdgcn_global_load_lds(
      (const __attribute__((address_space(1))) void*)g,
      (__attribute__((address_space(3))) void*)l, 16, 0, 0);
}

// ---------------------------------------------------------------------------
// TN-form bf16 MFMA GEMM: C[m,n] = sum_k A[m,k]*B[n,k], A:[M,K] B:[N,K],
// both k-contiguous bf16. 128x128 tile, BK=32, 256 thr = 4 waves (2x2 of
// 64x64), 16x16x32 MFMA. 1.5-stage pipeline: double-buffered LDS; loads for
// tile k+1 are issued AFTER the barrier and drained only at the NEXT
// iteration's barrier, so a full compute phase hides the load latency.
// XOR granule swizzle keeps LDS bank aliasing <= 2-way (free).
// ---------------------------------------------------------------------------
template<bool OUT_BF16, bool EPI>
__global__ __launch_bounds__(256)
void gemm_tn(const unsigned short* __restrict__ A, const unsigned short* __restrict__ B,
             void* __restrict__ Cout, int K, int lda, int ldb, int ldc,
             long long sA, long long sB, long long sC,
             const float* __restrict__ rs, const float* __restrict__ cs,
             int rcStride, float scale)
{
  const int bz = blockIdx.z;
  A += (long long)bz * sA;
  B += (long long)bz * sB;
  if (EPI) { rs += (long long)bz * rcStride; cs += (long long)bz * rcStride; }
  const int m0 = blockIdx.y * 128, n0 = blockIdx.x * 128;
  const int tid = threadIdx.x;
  const int w = tid >> 6, lane = tid & 63;
  const int wm = (w >> 1) * 64, wn = (w & 1) * 64;
  const int rl = lane & 15, qd = lane >> 4;

  __shared__ __align__(16) unsigned short As[2][128 * 32];
  __shared__ __align__(16) unsigned short Bs[2][128 * 32];

  // staging: wave w covers rows 32w..32w+31 of each tile (2 chunks of 16 rows)
  const int sr = lane >> 2, sg = lane & 3;
  const int ml0 = 32 * w + sr, ml1 = 32 * w + 16 + sr;
  const int q0 = sg ^ ((ml0 >> 1) & 3), q1 = sg ^ ((ml1 >> 1) & 3);
  const unsigned short* gA0 = A + (long long)(m0 + ml0) * lda + q0 * 8;
  const unsigned short* gA1 = A + (long long)(m0 + ml1) * lda + q1 * 8;
  const unsigned short* gB0 = B + (long long)(n0 + ml0) * ldb + q0 * 8;
  const unsigned short* gB1 = B + (long long)(n0 + ml1) * ldb + q1 * 8;
  const int lo0 = (32 * w) * 32, lo1 = (32 * w + 16) * 32;  // wave-uniform

  // fragment read offsets (swizzle-corrected)
  int aoff[4], boff[4];
  #pragma unroll
  for (int i = 0; i < 4; ++i) {
    const int mr = wm + i * 16 + rl;
    aoff[i] = mr * 32 + ((qd ^ ((mr >> 1) & 3)) * 8);
    const int nr = wn + i * 16 + rl;
    boff[i] = nr * 32 + ((qd ^ ((nr >> 1) & 3)) * 8);
  }

  floatx4 acc[4][4];
  #pragma unroll
  for (int i = 0; i < 4; ++i)
    #pragma unroll
    for (int j = 0; j < 4; ++j) acc[i][j] = 0.0f;

  // prologue: stage tile 0 into buffer 0
  gld16(gA0, As[0] + lo0); gld16(gA1, As[0] + lo1);
  gld16(gB0, Bs[0] + lo0); gld16(gB1, Bs[0] + lo1);

  int buf = 0;
  for (int kk = 0; kk < K; kk += 32, buf ^= 1) {
    __syncthreads();  // drains the loads for `buf` (issued one iter ago)
    if (kk + 32 < K) {
      const int nb = buf ^ 1, k2 = kk + 32;
      gld16(gA0 + k2, As[nb] + lo0); gld16(gA1 + k2, As[nb] + lo1);
      gld16(gB0 + k2, Bs[nb] + lo0); gld16(gB1 + k2, Bs[nb] + lo1);
    }
    short8 fa[4], fb[4];
    #pragma unroll
    for (int i = 0; i < 4; ++i) fa[i] = *(const short8*)(As[buf] + aoff[i]);
    #pragma unroll
    for (int j = 0; j < 4; ++j) fb[j] = *(const short8*)(Bs[buf] + boff[j]);
    #pragma unroll
    for (int i = 0; i < 4; ++i)
      #pragma unroll
      for (int j = 0; j < 4; ++j)
        acc[i][j] = __builtin_amdgcn_mfma_f32_16x16x32_bf16(fa[i], fb[j], acc[i][j], 0, 0, 0);
    // no second barrier: next iteration's barrier covers the WAR hazard
  }

  // epilogue: C/D layout col=lane&15, row=(lane>>4)*4+reg
  #pragma unroll
  for (int i = 0; i < 4; ++i) {
    #pragma unroll
    for (int r = 0; r < 4; ++r) {
      const int row = m0 + wm + i * 16 + qd * 4 + r;
      const float rowf = EPI ? rs[row] * scale : 0.f;
      #pragma unroll
      for (int j = 0; j < 4; ++j) {
        const int col = n0 + wn + j * 16 + rl;
        float v = acc[i][j][r];
        if (EPI) v *= rowf * cs[col];
        const long long idx = (long long)bz * sC + (long long)row * ldc + col;
        if (OUT_BF16) ((unsigned short*)Cout)[idx] = f2b(v);
        else          ((float*)Cout)[idx] = v;
      }
    }
  }
}

// ---------------------------------------------------------------------------
// x [B,C,T] fp32 -> xT [B,T,C] bf16 (transpose-convert, 32x32 LDS tiles)
// ---------------------------------------------------------------------------
__global__ __launch_bounds__(256)
void conv_xT(const float* __restrict__ x, unsigned short* __restrict__ xT)
{
  const int b = blockIdx.z, t0 = blockIdx.x * 32, c0 = blockIdx.y * 32;
  const int tx = threadIdx.x & 31, ty = threadIdx.x >> 5;
  __shared__ float tile[32][33];
  const float* src = x + (long long)b * C_ * T_;
  #pragma unroll
  for (int r = 0; r < 4; ++r)
    tile[ty + 8 * r][tx] = src[(long long)(c0 + ty + 8 * r) * T_ + t0 + tx];
  __syncthreads();
  unsigned short* dst = xT + (long long)b * T_ * C_;
  #pragma unroll
  for (int r = 0; r < 4; ++r)
    dst[(long long)(t0 + ty + 8 * r) * C_ + c0 + tx] = f2b(tile[tx][ty + 8 * r]);
}

__global__ __launch_bounds__(256)
void conv_bf(const float* __restrict__ in, unsigned short* __restrict__ out, int n)
{
  const int i = blockIdx.x * 256 + threadIdx.x;
  if (i < n) out[i] = f2b(in[i]);
}

// ---------------------------------------------------------------------------
// Depthwise-3 (zero pad) on v channels [2C,3C): bf16 in [B,3C,T] -> v [B,C,T]
// ---------------------------------------------------------------------------
__global__ __launch_bounds__(256)
void dw_v(const unsigned short* __restrict__ qkv, const float* __restrict__ wdw,
          unsigned short* __restrict__ vout)
{
  const long long idx = (long long)blockIdx.x * 256 + threadIdx.x;  // [B*C*T)
  const int t = (int)(idx % T_);
  const long long rem = idx / T_;
  const int c = (int)(rem % C_), b = (int)(rem / C_);
  const unsigned short* src = qkv + ((long long)(b * C3_ + 2 * C_ + c)) * T_;
  const float* wp = wdw + (2 * C_ + c) * 3;
  const float xm = (t > 0)      ? b2f(src[t - 1]) : 0.f;
  const float x0 = b2f(src[t]);
  const float xp = (t < T_ - 1) ? b2f(src[t + 1]) : 0.f;
  vout[(long long)(b * C_ + c) * T_ + t] = f2b(fmaf(wp[0], xm, fmaf(wp[1], x0, wp[2] * xp)));
}

// ---------------------------------------------------------------------------
// Depthwise-3 + transpose for q (p=0) / k (p=1): [B,3C,T] -> [B,T,C] bf16
// ---------------------------------------------------------------------------
__global__ __launch_bounds__(256)
void dw_qk_t(const unsigned short* __restrict__ qkv, const float* __restrict__ wdw,
             unsigned short* __restrict__ qT, unsigned short* __restrict__ kT)
{
  const int bz = blockIdx.z, b = bz >> 1, p = bz & 1;
  const int t0 = blockIdx.x * 32, c0 = blockIdx.y * 32;
  const int tx = threadIdx.x & 31, ty = threadIdx.x >> 5;
  __shared__ float tin[32][34];   // [c][t-1 .. t+32]
  __shared__ float tout[32][33];  // [t][c]
  const int chb = b * C3_ + p * C_;
  #pragma unroll
  for (int r = 0; r < 4; ++r) {
    const int cy = ty + 8 * r;
    const unsigned short* src = qkv + (long long)(chb + c0 + cy) * T_;
    int t = t0 - 1 + tx;
    tin[cy][tx] = (t >= 0 && t < T_) ? b2f(src[t]) : 0.f;
    if (tx < 2) {
      const int t2 = t0 + 31 + tx;
      tin[cy][32 + tx] = (t2 < T_) ? b2f(src[t2]) : 0.f;
    }
  }
  __syncthreads();
  #pragma unroll
  for (int r = 0; r < 4; ++r) {
    const int cy = ty + 8 * r;
    const float* wp = wdw + (long long)(p * C_ + c0 + cy) * 3;
    tout[tx][cy] = fmaf(wp[0], tin[cy][tx], fmaf(wp[1], tin[cy][tx + 1], wp[2] * tin[cy][tx + 2]));
  }
  __syncthreads();
  unsigned short* dst = (p == 0 ? qT : kT) + (long long)b * T_ * C_;
  #pragma unroll
  for (int r = 0; r < 4; ++r)
    dst[(long long)(t0 + ty + 8 * r) * C_ + c0 + tx] = f2b(tout[ty + 8 * r][tx]);
}

// ---------------------------------------------------------------------------
// Row L2-norm stats from bf16 [B*T, C] rows: inv = 1/max(||row||,eps)
// ---------------------------------------------------------------------------
__global__ __launch_bounds__(256)
void norms_k(const unsigned short* __restrict__ qT, const unsigned short* __restrict__ kT,
             float* __restrict__ inv_nq, float* __restrict__ inv_nk)
{
  const int wave = threadIdx.x >> 6, lane = threadIdx.x & 63;
  const long long row = (long long)blockIdx.x * 4 + wave;
  const unsigned short* src = (blockIdx.y == 0 ? qT : kT) + row * C_ + lane * 8;
  const uint4 u = *(const uint4*)src;
  float ss = 0.f;
  const unsigned int uu[4] = {u.x, u.y, u.z, u.w};
  #pragma unroll
  for (int i = 0; i < 4; ++i) {
    const float lo = b2f(uu[i] & 0xFFFF), hi = b2f(uu[i] >> 16);
    ss = fmaf(lo, lo, ss); ss = fmaf(hi, hi, ss);
  }
  #pragma unroll
  for (int m = 32; m; m >>= 1) ss += __shfl_xor(ss, m);
  if (lane == 0)
    (blockIdx.y == 0 ? inv_nq : inv_nk)[row] = 1.f / fmaxf(sqrtf(ss), 1e-12f);
}

// ---------------------------------------------------------------------------
// Row softmax: fp32 [rows, T] -> bf16 [rows, T]. 256 thr, 8 elems/thread.
// ---------------------------------------------------------------------------
__global__ __launch_bounds__(256)
void softmax_bf(const float* __restrict__ S, unsigned short* __restrict__ P)
{
  const float* src = S + (long long)blockIdx.x * T_;
  unsigned short* dst = P + (long long)blockIdx.x * T_;
  const int tid = threadIdx.x;
  __shared__ float red[256];
  const float4 v0 = ((const float4*)src)[tid * 2];
  const float4 v1 = ((const float4*)src)[tid * 2 + 1];
  float vals[8] = {v0.x, v0.y, v0.z, v0.w, v1.x, v1.y, v1.z, v1.w};
  float mx = vals[0];
  #pragma unroll
  for (int i = 1; i < 8; ++i) mx = fmaxf(mx, vals[i]);
  red[tid] = mx; __syncthreads();
  for (int s = 128; s > 0; s >>= 1) {
    if (tid < s) red[tid] = fmaxf(red[tid], red[tid + s]);
    __syncthreads();
  }
  mx = red[0]; __syncthreads();
  float sum = 0.f;
  #pragma unroll
  for (int i = 0; i < 8; ++i) { vals[i] = __expf(vals[i] - mx); sum += vals[i]; }
  red[tid] = sum; __syncthreads();
  for (int s = 128; s > 0; s >>= 1) {
    if (tid < s) red[tid] += red[tid + s];
    __syncthreads();
  }
  const float inv = 1.f / red[0];
  unsigned short o[8];
  #pragma unroll
  for (int i = 0; i < 8; ++i) o[i] = f2b(vals[i] * inv);
  uint4 pk;
  pk.x = (unsigned int)o[0] | ((unsigned int)o[1] << 16);
  pk.y = (unsigned int)o[2] | ((unsigned int)o[3] << 16);
  pk.z = (unsigned int)o[4] | ((unsigned int)o[5] << 16);
  pk.w = (unsigned int)o[6] | ((unsigned int)o[7] << 16);
  ((uint4*)dst)[tid] = pk;
}

// ---------------------------------------------------------------------------
// Workspace arena (bytes), total ~185.1 MB (layout unchanged from R2).
// ---------------------------------------------------------------------------
extern "C" void kernel_launch(void* const* d_in, const int* in_sizes, int n_in,
                              void* d_out, int out_size, void* d_ws, size_t ws_size,
                              hipStream_t stream)
{
  const float* x      = (const float*)d_in[0];
  const float* w_qkv  = (const float*)d_in[1];
  const float* w_dw   = (const float*)d_in[2];
  const float* w_proj = (const float*)d_in[3];
  float* out = (float*)d_out;

  char* base = (char*)d_ws;
  float*          scores  = (float*)base;
  unsigned short* xT      = (unsigned short*)base;                    // alias
  unsigned short* wqkv_bf = (unsigned short*)(base + 16777216);       // alias
  unsigned short* av_t    = (unsigned short*)base;                    // alias (late)
  char* p = base + 67108864;
  unsigned short* qT = (unsigned short*)p; p += 16777216;
  unsigned short* kT = (unsigned short*)p; p += 16777216;
  unsigned short* vb = (unsigned short*)p; p += 16777216;
  unsigned short* attn    = (unsigned short*)p;
  unsigned short* qkv_bf  = (unsigned short*)p;                       // alias (early)
  p += 67108864;
  unsigned short* wproj_bf = (unsigned short*)p; p += 524288;
  float* inv_nq = (float*)p; p += 65536;
  float* inv_nk = (float*)p;

  const long long TC = (long long)T_ * C_, TT = (long long)T_ * T_;

  // 0) conversions
  conv_xT<<<dim3(T_ / 32, C_ / 32, B_), 256, 0, stream>>>(x, xT);
  conv_bf<<<(C3_ * C_) / 256, 256, 0, stream>>>(w_qkv, wqkv_bf, C3_ * C_);
  conv_bf<<<(C_ * C_) / 256, 256, 0, stream>>>(w_proj, wproj_bf, C_ * C_);

  // 1) qkv[b][o][t] = sum_c wqkv[o][c] * x[c][t]
  gemm_tn<true, false><<<dim3(16, 12, B_), 256, 0, stream>>>(
      wqkv_bf, xT, qkv_bf, C_, C_, C_, T_,
      0LL, TC, (long long)C3_ * T_, nullptr, nullptr, 0, 1.f);

  // 2) depthwise conv
  dw_v<<<(int)(((long long)B_ * C_ * T_) / 256), 256, 0, stream>>>(qkv_bf, w_dw, vb);
  dw_qk_t<<<dim3(T_ / 32, C_ / 32, B_ * 2), 256, 0, stream>>>(qkv_bf, w_dw, qT, kT);

  // 3) channel-L2 stats (from bf16 values — exact normalization of rounded vecs)
  norms_k<<<dim3((B_ * T_) / 4, 2), 256, 0, stream>>>(qT, kT, inv_nq, inv_nk);

  // 4) scores + softmax, two half-batches of 4 (scores buffer reused)
  for (int h = 0; h < 2; ++h) {
    const long long o = (long long)h * 4;
    gemm_tn<false, true><<<dim3(16, 16, 4), 256, 0, stream>>>(
        qT + o * TC, kT + o * TC, scores, C_, C_, C_, T_,
        TC, TC, TT, inv_nq + o * T_, inv_nk + o * T_, T_, INV_TEMP);
    softmax_bf<<<4 * T_, 256, 0, stream>>>(scores, attn + o * TT);
  }

  // 5) av_t[b][t][c] = sum_s attn[t][s] * v[c][s]
  gemm_tn<true, false><<<dim3(4, 16, B_), 256, 0, stream>>>(
      attn, vb, av_t, T_, T_, T_, C_,
      TT, (long long)C_ * T_, TC, nullptr, nullptr, 0, 1.f);

  // 6) out[b][o][t] = sum_c wproj[o][c] * av_t[t][c]
  gemm_tn<false, false><<<dim3(16, 4, B_), 256, 0, stream>>>(
      wproj_bf, av_t, out, C_, C_, C_, T_,
      0LL, TC, (long long)C_ * T_, nullptr, nullptr, 0, 1.f);
}